// Round 7
// baseline (392.335 us; speedup 1.0000x reference)
//
#include <hip/hip_runtime.h>
#include <math.h>

// CIRNet: T=1048576 rows x 18 feats. Outputs concat: r_predicts[N], regs[N], dts[N], N=T-1.
// ONE launch, two internal phases separated by a device-wide ticket barrier:
//  phase 0 (prep): coalesced per-row coeff computation -> dc[] + seeds[] in ws,
//                  regs/dts to out.  (round-5 prep pattern, low VGPR, no scratch)
//  phase 1 (solve): per-thread 4-step Newton-linearized affine map from ODE seed ->
//                  block affine scan -> barrier -> global scan of 256 block aggregates ->
//                  replay -> float4 store.
// Cross-XCD visibility of dc/seeds inside one dispatch: __threadfence() release before
// barrier, __threadfence() acquire after (agent-scope L2 wb/inv), per guide G16.
// Per-step map: r' = a*r + b + c*sqrt(|r|), a = 1-k*d, b = k*th*d, c = sig*eps*sqrt(d).
// Pad step (n=NSTEPS) stored as (0,0) -> exact identity map.
#define NSTEPS  1048575
#define NPAD    1048576
#define FEAT    18
#define NT      1024
#define NB      256               // <= 256 CUs -> all blocks co-resident
#define TOT     (NT * NB)         // 262144
#define CHUNKS  TOT               // 4 steps per chunk

__device__ unsigned int g_ticket = 0;          // monotone ticket barrier (never reset;
                                               // generation arithmetic -> no init needed)
__device__ float gAb[NB], gBb[NB];             // block affine aggregates

__device__ __forceinline__ void device_barrier(int tid) {
    __syncthreads();
    if (tid == 0) {
        unsigned int tk = __hip_atomic_fetch_add(&g_ticket, 1u, __ATOMIC_ACQ_REL,
                                                 __HIP_MEMORY_SCOPE_AGENT);
        unsigned int target = (tk / NB + 1u) * NB;   // end of this barrier's generation
        while (__hip_atomic_load(&g_ticket, __ATOMIC_ACQUIRE, __HIP_MEMORY_SCOPE_AGENT) < target)
            __builtin_amdgcn_s_sleep(1);
    }
    __syncthreads();
}

// one step + derivative-product update
#define GSTEP(dd, cc) { \
    float a   = fmaf(-k, (dd), 1.f); \
    float b   = kth * (dd); \
    float ar  = fabsf(r); \
    float sq  = sqrtf(ar); \
    float inv = (ar > 1e-30f) ? rsqrtf(ar) : 0.f; \
    float g   = fmaf(0.5f * (cc), copysignf(inv, r), a); \
    r = fmaf((cc), sq, fmaf(a, r, b)); \
    P *= g; }

#define FSTEP(dd, cc) { \
    float a = fmaf(-k, (dd), 1.f); \
    float b = kth * (dd); \
    rr = fmaf((cc), sqrtf(fabsf(rr)), fmaf(a, rr, b)); }

__device__ __forceinline__ void wave_scan_affine(float& A, float& B, int lane) {
#pragma unroll
    for (int d = 1; d < 64; d <<= 1) {
        float pA = __shfl_up(A, d, 64);
        float pB = __shfl_up(B, d, 64);
        if (lane >= d) { B = fmaf(A, pB, B); A *= pA; }
    }
}

__global__ void __launch_bounds__(NT) cir_one(
    const float* __restrict__ trace,
    const float* __restrict__ sW, const float* __restrict__ sb,
    const float* __restrict__ eW, const float* __restrict__ kp,
    const float* __restrict__ thp,
    float* __restrict__ out,
    float2* __restrict__ dc, float* __restrict__ seeds)
{
    __shared__ float wAs[16], wBs[16];
    __shared__ float sgA[NB], sgB[NB];
    const int tid = threadIdx.x, lane = tid & 63, wid = tid >> 6, bid = blockIdx.x;
    const int g = bid * NT + tid;

    const float k = kp[0], th = thp[0], kth = k * th;
    const float sbv = sb[0];
    const float r0 = trace[1];
    const float t0 = trace[0];
    float sWv[8], eWv[8];
#pragma unroll
    for (int j = 0; j < 8; ++j) { sWv[j] = sW[j]; eWv[j] = eW[j]; }

    // ---------------- phase 0: prep (coalesced grid-stride, round-5 pattern) ----------------
#pragma unroll
    for (int i = 0; i < 4; ++i) {
        int n = g + i * TOT;
        if (n < NSTEPS) {
            const float2* r2 = (const float2*)(trace + (long)n * FEAT);
            float2 e0 = r2[0], e1 = r2[1], e2 = r2[2], e3 = r2[3], e4 = r2[4];
            float2 e5 = r2[5], e6 = r2[6], e7 = r2[7], e8 = r2[8];
            float tn1 = trace[(long)(n + 1) * FEAT];
            float d = tn1 - e0.x;
            float sig = sbv;
            sig = fmaf(e1.x, sWv[0], sig); sig = fmaf(e1.y, sWv[1], sig);
            sig = fmaf(e2.x, sWv[2], sig); sig = fmaf(e2.y, sWv[3], sig);
            sig = fmaf(e3.x, sWv[4], sig); sig = fmaf(e3.y, sWv[5], sig);
            sig = fmaf(e4.x, sWv[6], sig); sig = fmaf(e4.y, sWv[7], sig);
            float ep = 0.f;
            ep = fmaf(e5.x, eWv[0], ep); ep = fmaf(e5.y, eWv[1], ep);
            ep = fmaf(e6.x, eWv[2], ep); ep = fmaf(e6.y, eWv[3], ep);
            ep = fmaf(e7.x, eWv[4], ep); ep = fmaf(e7.y, eWv[5], ep);
            ep = fmaf(e8.x, eWv[6], ep); ep = fmaf(e8.y, eWv[7], ep);
            dc[n] = make_float2(d, sig * ep * sqrtf(fabsf(d)));
            out[NSTEPS + n]     = fmaf(-sig, sig, 2.f * k * th);  // regs
            out[2 * NSTEPS + n] = d;                              // dts
            if ((n & 3) == 0)   // ODE closed-form chunk seed (TOT%4==0 -> uniform branch per i)
                seeds[n >> 2] = th + (r0 - th) * __expf(-k * (e0.x - t0));
        } else {
            dc[n] = make_float2(0.f, 0.f);   // exact identity pad (n==NSTEPS only)
        }
    }

    // ---------------- cross-XCD handoff: release -> barrier -> acquire ----------------
    __threadfence();          // drain this thread's dc/seeds writes to device scope
    device_barrier(tid);
    __threadfence();          // invalidate stale cached lines before reading others' dc

    // ---------------- phase 1: 4-step linearized forward from seed ----------------
    const int c = g;
    const float4 q0 = ((const float4*)dc)[2 * c];       // (d0,c0,d1,c1)
    const float4 q1 = ((const float4*)dc)[2 * c + 1];   // (d2,c2,d3,c3)
    const float s = seeds[c];
    float r = s, P = 1.f;
    GSTEP(q0.x, q0.y)
    GSTEP(q0.z, q0.w)
    GSTEP(q1.x, q1.y)
    GSTEP(q1.z, q1.w)
    float A = P, B = fmaf(-P, s, r);

    // ---- block-level inclusive scan over 1024 thread maps ----
    float iA = A, iB = B;
    wave_scan_affine(iA, iB, lane);
    if (lane == 63) { wAs[wid] = iA; wBs[wid] = iB; }
    __syncthreads();
    if (wid == 0) {
        float aA = (lane < 16) ? wAs[lane] : 1.f;
        float aB = (lane < 16) ? wBs[lane] : 0.f;
        wave_scan_affine(aA, aB, lane);
        if (lane < 16) { wAs[lane] = aA; wBs[lane] = aB; }
    }
    __syncthreads();
    float weA = 1.f, weB = 0.f;
    if (wid > 0) { weA = wAs[wid - 1]; weB = wBs[wid - 1]; }
    float eA = __shfl_up(iA, 1, 64), eB = __shfl_up(iB, 1, 64);
    if (lane == 0) { eA = 1.f; eB = 0.f; }
    float Ate = eA * weA;                 // thread-exclusive prefix within block
    float Bte = fmaf(eA, weB, eB);

    // ---- publish block aggregate (AGENT-scope ops bypass to coherence point) ----
    if (tid == 0) {
        __hip_atomic_store(&gAb[bid], wAs[15], __ATOMIC_RELAXED, __HIP_MEMORY_SCOPE_AGENT);
        __hip_atomic_store(&gBb[bid], wBs[15], __ATOMIC_RELEASE, __HIP_MEMORY_SCOPE_AGENT);
    }
    device_barrier(tid);

    // ---- every block redundantly scans the 256 block aggregates ----
    if (tid < NB) {
        sgA[tid] = __hip_atomic_load(&gAb[tid], __ATOMIC_RELAXED, __HIP_MEMORY_SCOPE_AGENT);
        sgB[tid] = __hip_atomic_load(&gBb[tid], __ATOMIC_RELAXED, __HIP_MEMORY_SCOPE_AGENT);
    }
    __syncthreads();
    for (int d = 1; d < NB; d <<= 1) {
        float pA = 1.f, pB = 0.f;
        bool act = (tid < NB) && (tid >= d);
        if (act) { pA = sgA[tid - d]; pB = sgB[tid - d]; }
        __syncthreads();
        if (act) { sgB[tid] = fmaf(sgA[tid], pB, sgB[tid]); sgA[tid] *= pA; }
        __syncthreads();
    }
    float beA = 1.f, beB = 0.f;
    if (bid > 0) { beA = sgA[bid - 1]; beB = sgB[bid - 1]; }

    // ---- corrected start, replay 4 steps, store r_predicts ----
    float FA = Ate * beA;
    float FB = fmaf(Ate, beB, Bte);
    float rr = fmaf(FA, r0, FB);
    float4 ov;
    FSTEP(q0.x, q0.y) ov.x = rr;
    FSTEP(q0.z, q0.w) ov.y = rr;
    FSTEP(q1.x, q1.y) ov.z = rr;
    FSTEP(q1.z, q1.w) ov.w = rr;
    int nb = 4 * c;
    if (nb + 4 <= NSTEPS) {
        *(float4*)(out + nb) = ov;
    } else {                       // last thread only (step NSTEPS is pad)
        out[nb + 0] = ov.x;
        out[nb + 1] = ov.y;
        out[nb + 2] = ov.z;
    }
}

extern "C" void kernel_launch(void* const* d_in, const int* in_sizes, int n_in,
                              void* d_out, int out_size, void* d_ws, size_t ws_size,
                              hipStream_t stream)
{
    const float* trace = (const float*)d_in[0];
    const float* sW    = (const float*)d_in[1];
    const float* sb    = (const float*)d_in[2];
    const float* eW    = (const float*)d_in[3];
    const float* kp    = (const float*)d_in[4];
    const float* thp   = (const float*)d_in[5];
    float* out = (float*)d_out;

    float*  w     = (float*)d_ws;
    float2* dc    = (float2*)w;          // NPAD float2 = 8 MB
    float*  seeds = w + 2 * NPAD;        // CHUNKS floats = 1 MB

    cir_one<<<NB, NT, 0, stream>>>(trace, sW, sb, eW, kp, thp, out, dc, seeds);
}

// Round 8
// 274.065 us; speedup vs baseline: 1.4315x; 1.4315x over previous
//
#include <hip/hip_runtime.h>
#include <math.h>

// CIRNet: T=1048576 rows x 18 feats. Outputs concat: r_predicts[N], regs[N], dts[N], N=T-1.
// ONE launch, 1024 blocks x 256 threads, __launch_bounds__(256,4) -> 4 blocks/CU
// guaranteed co-resident (ticket barrier safe).
// Block b owns rows [1024b, 1024b+1024): phase 0 computes per-step (d, c=sig*eps*sqrt(d))
// into LDS (no global scratch, no cross-XCD handoff for step data), writes regs/dts.
// Phase 1: per-thread 4-step Newton-linearized affine map from ODE closed-form seed ->
// block affine scan (wave shuffle + LDS) -> device ticket barrier (only for the 1024
// block aggregates) -> redundant global scan -> replay 4 steps -> float4 store.
// Per-step map: r' = a*r + b + c*sqrt(|r|), a = 1-k*d, b = k*th*d.
// Pad step (n=NSTEPS) uses (d,c)=(0,0) -> exact identity map.
#define NSTEPS  1048575
#define FEAT    18
#define NT      256
#define NBLK    1024
#define RPB     1024              // rows per block = NT*4

__device__ unsigned int g_ticket = 0;          // monotone ticket barrier (never reset;
                                               // generation arithmetic -> no init needed)
__device__ float gAb[NBLK], gBb[NBLK];         // block affine aggregates

// one step + derivative-product update
#define GSTEP(dd, cc) { \
    float a   = fmaf(-k, (dd), 1.f); \
    float bb  = kth * (dd); \
    float ar  = fabsf(r); \
    float sq  = sqrtf(ar); \
    float inv = (ar > 1e-30f) ? rsqrtf(ar) : 0.f; \
    float g   = fmaf(0.5f * (cc), copysignf(inv, r), a); \
    r = fmaf((cc), sq, fmaf(a, r, bb)); \
    P *= g; }

#define FSTEP(dd, cc) { \
    float a  = fmaf(-k, (dd), 1.f); \
    float bb = kth * (dd); \
    rr = fmaf((cc), sqrtf(fabsf(rr)), fmaf(a, rr, bb)); }

__device__ __forceinline__ void wave_scan_affine(float& A, float& B, int lane) {
#pragma unroll
    for (int d = 1; d < 64; d <<= 1) {
        float pA = __shfl_up(A, d, 64);
        float pB = __shfl_up(B, d, 64);
        if (lane >= d) { B = fmaf(A, pB, B); A *= pA; }
    }
}

__global__ void __launch_bounds__(NT, 4) cir_one(
    const float* __restrict__ trace,
    const float* __restrict__ sW, const float* __restrict__ sb,
    const float* __restrict__ eW, const float* __restrict__ kp,
    const float* __restrict__ thp,
    float* __restrict__ out)
{
    __shared__ float2 dcs[RPB];                // 8 KB: per-row (d, c)
    __shared__ float  seeds_s[NT];             // 1 KB: per-chunk ODE seed
    __shared__ float  wA4[4], wB4[4];          // wave aggregates (block scan)
    __shared__ float  sgA[NBLK], sgB[NBLK];    // 8 KB: scanned block aggregates

    const int t = threadIdx.x, lane = t & 63, wid = t >> 6, b = blockIdx.x;
    const float k = kp[0], th = thp[0], kth = k * th;
    const float r0 = trace[1], t0 = trace[0];
    const float sbv = sb[0];
    float sWv[8], eWv[8];
#pragma unroll
    for (int j = 0; j < 8; ++j) { sWv[j] = sW[j]; eWv[j] = eW[j]; }

    // ---------------- phase 0: rows -> LDS coeffs + regs/dts (2-row load batches) ----------
    const int nbase = b * RPB;
#pragma unroll
    for (int p = 0; p < 2; ++p) {
        float2 R[2][9];
        float tn1[2];
        int   n[2];
        bool  v[2];
#pragma unroll
        for (int u = 0; u < 2; ++u) {              // issue ALL loads before any use
            int i = 2 * p + u;
            n[u] = nbase + t + i * NT;
            v[u] = (n[u] < NSTEPS);
            if (v[u]) {
                const float2* r2 = (const float2*)(trace + (long)n[u] * FEAT);
#pragma unroll
                for (int j = 0; j < 9; ++j) R[u][j] = r2[j];
                tn1[u] = trace[(long)(n[u] + 1) * FEAT];
            }
        }
#pragma unroll
        for (int u = 0; u < 2; ++u) {
            int i = 2 * p + u;
            int l = t + i * NT;                    // local row index
            if (v[u]) {
                float d = tn1[u] - R[u][0].x;
                float sig = sbv;
#pragma unroll
                for (int j = 0; j < 4; ++j) {
                    sig = fmaf(R[u][1 + j].x, sWv[2 * j],     sig);
                    sig = fmaf(R[u][1 + j].y, sWv[2 * j + 1], sig);
                }
                float ep = 0.f;
#pragma unroll
                for (int j = 0; j < 4; ++j) {
                    ep = fmaf(R[u][5 + j].x, eWv[2 * j],     ep);
                    ep = fmaf(R[u][5 + j].y, eWv[2 * j + 1], ep);
                }
                dcs[l] = make_float2(d, sig * ep * sqrtf(fabsf(d)));
                out[NSTEPS + n[u]]     = fmaf(-sig, sig, 2.f * kth);  // regs
                out[2 * NSTEPS + n[u]] = d;                           // dts
                if ((t & 3) == 0)      // row n%4==0 -> chunk seed (lc = l/4 = t/4 + i*64)
                    seeds_s[(t >> 2) + i * 64] =
                        th + (r0 - th) * __expf(-k * (R[u][0].x - t0));
            } else {
                dcs[l] = make_float2(0.f, 0.f);    // exact identity pad (n==NSTEPS only)
            }
        }
    }
    __syncthreads();

    // ---------------- phase 1: 4-step linearized forward from seed ----------------
    const float4 q0 = ((const float4*)dcs)[2 * t];       // (d0,c0,d1,c1)
    const float4 q1 = ((const float4*)dcs)[2 * t + 1];   // (d2,c2,d3,c3)
    const float s = seeds_s[t];
    float r = s, P = 1.f;
    GSTEP(q0.x, q0.y)
    GSTEP(q0.z, q0.w)
    GSTEP(q1.x, q1.y)
    GSTEP(q1.z, q1.w)

    // ---- block-level scan over 256 thread maps ----
    float iA = P, iB = fmaf(-P, s, r);
    wave_scan_affine(iA, iB, lane);
    if (lane == 63) { wA4[wid] = iA; wB4[wid] = iB; }
    __syncthreads();
    float weA = 1.f, weB = 0.f;
#pragma unroll
    for (int wm = 0; wm < 3; ++wm)
        if (wm < wid) { weB = fmaf(wA4[wm], weB, wB4[wm]); weA *= wA4[wm]; }
    float eA = __shfl_up(iA, 1, 64), eB = __shfl_up(iB, 1, 64);
    if (lane == 0) { eA = 1.f; eB = 0.f; }
    float Ate = eA * weA;                 // thread-exclusive prefix within block
    float Bte = fmaf(eA, weB, eB);

    // ---- publish block aggregate + device-wide ticket barrier (1024 blocks) ----
    if (t == NT - 1) {                    // this thread holds wave-3 inclusive (iA,iB)
        float Ab = iA * weA;
        float Bb = fmaf(iA, weB, iB);
        __hip_atomic_store(&gAb[b], Ab, __ATOMIC_RELAXED, __HIP_MEMORY_SCOPE_AGENT);
        __hip_atomic_store(&gBb[b], Bb, __ATOMIC_RELEASE, __HIP_MEMORY_SCOPE_AGENT);
        unsigned int tk = __hip_atomic_fetch_add(&g_ticket, 1u, __ATOMIC_ACQ_REL,
                                                 __HIP_MEMORY_SCOPE_AGENT);
        unsigned int target = (tk / NBLK + 1u) * NBLK;
        while (__hip_atomic_load(&g_ticket, __ATOMIC_ACQUIRE, __HIP_MEMORY_SCOPE_AGENT) < target)
            __builtin_amdgcn_s_sleep(1);
    }
    __syncthreads();

    // ---- every block redundantly scans the 1024 block aggregates (4 per thread) ----
    float A4[4], B4[4];
#pragma unroll
    for (int j = 0; j < 4; ++j) {
        A4[j] = __hip_atomic_load(&gAb[4 * t + j], __ATOMIC_RELAXED, __HIP_MEMORY_SCOPE_AGENT);
        B4[j] = __hip_atomic_load(&gBb[4 * t + j], __ATOMIC_RELAXED, __HIP_MEMORY_SCOPE_AGENT);
    }
    float tA = 1.f, tB = 0.f;
#pragma unroll
    for (int j = 0; j < 4; ++j) { tB = fmaf(A4[j], tB, B4[j]); tA *= A4[j]; }
    float jA = tA, jB = tB;
    wave_scan_affine(jA, jB, lane);
    if (lane == 63) { wA4[wid] = jA; wB4[wid] = jB; }
    __syncthreads();
    float vA = 1.f, vB = 0.f;
#pragma unroll
    for (int wm = 0; wm < 3; ++wm)
        if (wm < wid) { vB = fmaf(wA4[wm], vB, wB4[wm]); vA *= wA4[wm]; }
    float xA = __shfl_up(jA, 1, 64), xB = __shfl_up(jB, 1, 64);
    if (lane == 0) { xA = 1.f; xB = 0.f; }
    float cA = xA * vA;                  // exclusive prefix over previous 4-groups
    float cB = fmaf(xA, vB, xB);
#pragma unroll
    for (int j = 0; j < 4; ++j) {        // inclusive values for all 1024 indices -> LDS
        cB = fmaf(A4[j], cB, B4[j]); cA *= A4[j];
        sgA[4 * t + j] = cA; sgB[4 * t + j] = cB;
    }
    __syncthreads();
    float beA = 1.f, beB = 0.f;
    if (b > 0) { beA = sgA[b - 1]; beB = sgB[b - 1]; }

    // ---- corrected start, replay 4 steps, store r_predicts ----
    float FA = Ate * beA;
    float FB = fmaf(Ate, beB, Bte);
    float rr = fmaf(FA, r0, FB);
    float4 ov;
    FSTEP(q0.x, q0.y) ov.x = rr;
    FSTEP(q0.z, q0.w) ov.y = rr;
    FSTEP(q1.x, q1.y) ov.z = rr;
    FSTEP(q1.z, q1.w) ov.w = rr;
    int nb = nbase + 4 * t;
    if (nb + 4 <= NSTEPS) {
        *(float4*)(out + nb) = ov;
    } else {                       // last thread only (step NSTEPS is pad)
        out[nb + 0] = ov.x;
        out[nb + 1] = ov.y;
        out[nb + 2] = ov.z;
    }
}

extern "C" void kernel_launch(void* const* d_in, const int* in_sizes, int n_in,
                              void* d_out, int out_size, void* d_ws, size_t ws_size,
                              hipStream_t stream)
{
    const float* trace = (const float*)d_in[0];
    const float* sW    = (const float*)d_in[1];
    const float* sb    = (const float*)d_in[2];
    const float* eW    = (const float*)d_in[3];
    const float* kp    = (const float*)d_in[4];
    const float* thp   = (const float*)d_in[5];
    float* out = (float*)d_out;

    cir_one<<<NBLK, NT, 0, stream>>>(trace, sW, sb, eW, kp, thp, out);
}

// Round 9
// 132.987 us; speedup vs baseline: 2.9502x; 2.0608x over previous
//
#include <hip/hip_runtime.h>
#include <math.h>

// CIRNet: T=1048576 rows x 18 feats. Outputs concat: r_predicts[N], regs[N], dts[N], N=T-1.
// Two launches (proven R5 skeleton; single-launch loses to compiler low-VGPR scheduling):
//  K1 prep: one thread per PAIR of rows -> 9 contiguous float4 loads (144B stride,
//           16B-aligned, 9-deep MLP). t[n+1] for second row via __shfl_down.
//           Writes dc[] (d, c=sig*eps*sqrt(d)), seeds[] (ODE closed form), regs/dts.
//  K2 fused: per-thread 4-step Newton-linearized affine map -> block scan ->
//           init-free device ticket barrier (256 co-resident blocks) -> global scan ->
//           replay -> float4 store.
// Per-step map: r' = a*r + b + c*sqrt(|r|), a = 1-k*d, b = k*th*d.
// Pad step (n=NSTEPS) stored as (0,0) -> exact identity map.
#define NSTEPS  1048575
#define NPAD    1048576
#define FEAT    18
#define PAIRS   (NPAD / 2)        // 524288
#define CHUNKS  (NPAD / 4)        // 262144
#define K2B     256               // 1024-thread blocks -> 1/CU -> co-resident
#define K2T     1024

__device__ unsigned int g_ticket = 0;      // monotone ticket barrier (never reset;
                                           // generation arithmetic -> no init needed)
__device__ float gAb[K2B], gBb[K2B];       // block affine aggregates

// ---------------- K1: pair-of-rows prep ----------------
__global__ void __launch_bounds__(256) prep_kernel(
    const float* __restrict__ trace,
    const float* __restrict__ sW, const float* __restrict__ sb,
    const float* __restrict__ eW, const float* __restrict__ kp,
    const float* __restrict__ thp,
    float2* __restrict__ dc, float* __restrict__ seeds,
    float* __restrict__ out)
{
    const int p = blockIdx.x * blockDim.x + threadIdx.x;   // pair id, grid covers PAIRS
    const int lane = threadIdx.x & 63;

    // 9 contiguous float4 loads: rows 2p (L[0..17]) and 2p+1 (L[18..35])
    const float4* q = (const float4*)(trace + 36l * p);
    float4 R0 = q[0], R1 = q[1], R2 = q[2], R3 = q[3], R4 = q[4];
    float4 R5 = q[5], R6 = q[6], R7 = q[7], R8 = q[8];

    // t_{2p+2} = neighbor's R0.x; lane 63 loads it (guarded)
    float nt = __shfl_down(R0.x, 1, 64);
    if (lane == 63) nt = (p + 1 < PAIRS) ? trace[36l * (p + 1)] : 0.f;

    const float k = kp[0], th = thp[0];
    const float sbv = sb[0];
    const bool  v1 = (p < PAIRS - 1);      // row 2p+1 == NSTEPS only for last pair

    // row 0: t=R0.x, sigma feats R0.z..R2.y, eps feats R2.z..R4.y, t_next=R4.z
    float sig0 = sbv;
    sig0 = fmaf(R0.z, sW[0], sig0); sig0 = fmaf(R0.w, sW[1], sig0);
    sig0 = fmaf(R1.x, sW[2], sig0); sig0 = fmaf(R1.y, sW[3], sig0);
    sig0 = fmaf(R1.z, sW[4], sig0); sig0 = fmaf(R1.w, sW[5], sig0);
    sig0 = fmaf(R2.x, sW[6], sig0); sig0 = fmaf(R2.y, sW[7], sig0);
    float ep0 = 0.f;
    ep0 = fmaf(R2.z, eW[0], ep0); ep0 = fmaf(R2.w, eW[1], ep0);
    ep0 = fmaf(R3.x, eW[2], ep0); ep0 = fmaf(R3.y, eW[3], ep0);
    ep0 = fmaf(R3.z, eW[4], ep0); ep0 = fmaf(R3.w, eW[5], ep0);
    ep0 = fmaf(R4.x, eW[6], ep0); ep0 = fmaf(R4.y, eW[7], ep0);
    float d0 = R4.z - R0.x;

    // row 1: t=R4.z, sigma feats R5.x..R6.w, eps feats R7.x..R8.w, t_next=nt
    float sig1 = sbv;
    sig1 = fmaf(R5.x, sW[0], sig1); sig1 = fmaf(R5.y, sW[1], sig1);
    sig1 = fmaf(R5.z, sW[2], sig1); sig1 = fmaf(R5.w, sW[3], sig1);
    sig1 = fmaf(R6.x, sW[4], sig1); sig1 = fmaf(R6.y, sW[5], sig1);
    sig1 = fmaf(R6.z, sW[6], sig1); sig1 = fmaf(R6.w, sW[7], sig1);
    float ep1 = 0.f;
    ep1 = fmaf(R7.x, eW[0], ep1); ep1 = fmaf(R7.y, eW[1], ep1);
    ep1 = fmaf(R7.z, eW[2], ep1); ep1 = fmaf(R7.w, eW[3], ep1);
    ep1 = fmaf(R8.x, eW[4], ep1); ep1 = fmaf(R8.y, eW[5], ep1);
    ep1 = fmaf(R8.z, eW[6], ep1); ep1 = fmaf(R8.w, eW[7], ep1);
    float d1 = nt - R4.z;

    // dc: one float4 store (16B aligned), pad pair -> identity (0,0)
    float c0 = sig0 * ep0 * sqrtf(fabsf(d0));
    float c1 = v1 ? sig1 * ep1 * sqrtf(fabsf(d1)) : 0.f;
    ((float4*)dc)[p] = make_float4(d0, c0, v1 ? d1 : 0.f, c1);

    // regs / dts outputs
    const int n = 2 * p;
    float kth2 = 2.f * k * th;
    out[NSTEPS + n] = fmaf(-sig0, sig0, kth2);
    if (v1) {
        out[NSTEPS + n + 1] = fmaf(-sig1, sig1, kth2);
        *(float2*)(out + 2 * NSTEPS + n) = make_float2(d0, d1);   // 8B-aligned
    } else {
        out[2 * NSTEPS + n] = d0;
    }

    // ODE closed-form chunk seed (chunk = 4 rows; even p owns chunk p/2)
    if ((p & 1) == 0)
        seeds[p >> 1] = th + (trace[1] - th) * __expf(-k * (R0.x - trace[0]));
}

// one step + derivative-product update
#define GSTEP(dd, cc) { \
    float a   = fmaf(-k, (dd), 1.f); \
    float b   = kth * (dd); \
    float ar  = fabsf(r); \
    float sq  = sqrtf(ar); \
    float inv = (ar > 1e-30f) ? rsqrtf(ar) : 0.f; \
    float g   = fmaf(0.5f * (cc), copysignf(inv, r), a); \
    r = fmaf((cc), sq, fmaf(a, r, b)); \
    P *= g; }

#define FSTEP(dd, cc) { \
    float a = fmaf(-k, (dd), 1.f); \
    float b = kth * (dd); \
    rr = fmaf((cc), sqrtf(fabsf(rr)), fmaf(a, rr, b)); }

__device__ __forceinline__ void wave_scan_affine(float& A, float& B, int lane) {
#pragma unroll
    for (int d = 1; d < 64; d <<= 1) {
        float pA = __shfl_up(A, d, 64);
        float pB = __shfl_up(B, d, 64);
        if (lane >= d) { B = fmaf(A, pB, B); A *= pA; }
    }
}

// ---------------- K2: fused chunk + scan + final (R5-proven) ----------------
__global__ void __launch_bounds__(K2T) fused_pass(
    const float2* __restrict__ dc, const float* __restrict__ seeds,
    const float* __restrict__ trace,
    const float* __restrict__ kp, const float* __restrict__ thp,
    float* __restrict__ out)
{
    __shared__ float wAs[16], wBs[16];
    __shared__ float sgA[K2B], sgB[K2B];
    const int tid = threadIdx.x, lane = tid & 63, wid = tid >> 6, bid = blockIdx.x;
    const int c = bid * K2T + tid;
    const float k = kp[0], th = thp[0], kth = k * th;
    const float4 q0 = ((const float4*)dc)[2 * c];       // (d0,c0,d1,c1)
    const float4 q1 = ((const float4*)dc)[2 * c + 1];   // (d2,c2,d3,c3)
    const float s = seeds[c];

    // forward 4 steps from seed, derivative product -> affine map x -> A*x+B
    float r = s, P = 1.f;
    GSTEP(q0.x, q0.y)
    GSTEP(q0.z, q0.w)
    GSTEP(q1.x, q1.y)
    GSTEP(q1.z, q1.w)
    float A = P, B = fmaf(-P, s, r);

    // block-level inclusive scan over 1024 thread maps
    float iA = A, iB = B;
    wave_scan_affine(iA, iB, lane);
    if (lane == 63) { wAs[wid] = iA; wBs[wid] = iB; }
    __syncthreads();
    if (wid == 0) {
        float aA = (lane < 16) ? wAs[lane] : 1.f;
        float aB = (lane < 16) ? wBs[lane] : 0.f;
        wave_scan_affine(aA, aB, lane);
        if (lane < 16) { wAs[lane] = aA; wBs[lane] = aB; }
    }
    __syncthreads();
    float weA = 1.f, weB = 0.f;
    if (wid > 0) { weA = wAs[wid - 1]; weB = wBs[wid - 1]; }
    float eA = __shfl_up(iA, 1, 64), eB = __shfl_up(iB, 1, 64);
    if (lane == 0) { eA = 1.f; eB = 0.f; }
    float Ate = eA * weA;                 // thread-exclusive prefix within block
    float Bte = fmaf(eA, weB, eB);

    // publish block aggregate + init-free device-wide ticket barrier
    if (tid == 0) {
        __hip_atomic_store(&gAb[bid], wAs[15], __ATOMIC_RELAXED, __HIP_MEMORY_SCOPE_AGENT);
        __hip_atomic_store(&gBb[bid], wBs[15], __ATOMIC_RELEASE, __HIP_MEMORY_SCOPE_AGENT);
        unsigned int tk = __hip_atomic_fetch_add(&g_ticket, 1u, __ATOMIC_ACQ_REL,
                                                 __HIP_MEMORY_SCOPE_AGENT);
        unsigned int target = (tk / K2B + 1u) * K2B;
        while (__hip_atomic_load(&g_ticket, __ATOMIC_ACQUIRE, __HIP_MEMORY_SCOPE_AGENT) < target)
            __builtin_amdgcn_s_sleep(1);
    }
    __syncthreads();

    // every block redundantly scans the 256 block aggregates
    if (tid < K2B) {
        sgA[tid] = __hip_atomic_load(&gAb[tid], __ATOMIC_RELAXED, __HIP_MEMORY_SCOPE_AGENT);
        sgB[tid] = __hip_atomic_load(&gBb[tid], __ATOMIC_RELAXED, __HIP_MEMORY_SCOPE_AGENT);
    }
    __syncthreads();
    for (int d = 1; d < K2B; d <<= 1) {
        float pA = 1.f, pB = 0.f;
        bool act = (tid < K2B) && (tid >= d);
        if (act) { pA = sgA[tid - d]; pB = sgB[tid - d]; }
        __syncthreads();
        if (act) { sgB[tid] = fmaf(sgA[tid], pB, sgB[tid]); sgA[tid] *= pA; }
        __syncthreads();
    }
    float beA = 1.f, beB = 0.f;
    if (bid > 0) { beA = sgA[bid - 1]; beB = sgB[bid - 1]; }

    // corrected start for this thread's 4 steps, replay, store
    float FA = Ate * beA;
    float FB = fmaf(Ate, beB, Bte);
    float rr = fmaf(FA, trace[1], FB);
    float4 ov;
    FSTEP(q0.x, q0.y) ov.x = rr;
    FSTEP(q0.z, q0.w) ov.y = rr;
    FSTEP(q1.x, q1.y) ov.z = rr;
    FSTEP(q1.z, q1.w) ov.w = rr;
    int nb = 4 * c;
    if (nb + 4 <= NSTEPS) {
        *(float4*)(out + nb) = ov;
    } else {                       // last thread only (step NSTEPS is pad)
        out[nb + 0] = ov.x;
        out[nb + 1] = ov.y;
        out[nb + 2] = ov.z;
    }
}

extern "C" void kernel_launch(void* const* d_in, const int* in_sizes, int n_in,
                              void* d_out, int out_size, void* d_ws, size_t ws_size,
                              hipStream_t stream)
{
    const float* trace = (const float*)d_in[0];
    const float* sW    = (const float*)d_in[1];
    const float* sb    = (const float*)d_in[2];
    const float* eW    = (const float*)d_in[3];
    const float* kp    = (const float*)d_in[4];
    const float* thp   = (const float*)d_in[5];
    float* out = (float*)d_out;

    float*  w     = (float*)d_ws;
    float2* dc    = (float2*)w;          // NPAD float2 = 8 MB
    float*  seeds = w + 2 * NPAD;        // CHUNKS floats = 1 MB

    prep_kernel<<<PAIRS / 256, 256, 0, stream>>>(trace, sW, sb, eW, kp, thp,
                                                 dc, seeds, out);
    fused_pass<<<K2B, K2T, 0, stream>>>(dc, seeds, trace, kp, thp, out);
}

// Round 10
// 129.635 us; speedup vs baseline: 3.0265x; 1.0259x over previous
//
#include <hip/hip_runtime.h>
#include <math.h>

// CIRNet: T=1048576 rows x 18 feats. Outputs concat: r_predicts[N], regs[N], dts[N], N=T-1.
// Two launches (best-measured skeleton, R5=128.7us):
//  K1 prep (R5 form): one thread per row, 9 float2 loads; writes dc[] (d, c=sig*eps*sqrt(d)),
//      seeds[] (ODE closed form per 4-step chunk), regs/dts outputs.
//  K2 fused: per-thread 4-step Newton-linearized affine map -> block scan ->
//      init-free device ticket barrier (256 co-resident 1024-thread blocks) ->
//      redundant global scan -> replay -> float4 store.
// Per-step map: r' = a*r + b + c*sqrt(|r|), a = 1-k*d, b = k*th*d.
// Pad step (n=NSTEPS) stored as (0,0) -> exact identity map.
#define NSTEPS  1048575
#define NPAD    1048576
#define FEAT    18
#define CHUNKS  (NPAD / 4)        // 262144
#define K2B     256
#define K2T     1024

__device__ unsigned int g_ticket = 0;      // monotone ticket barrier (never reset;
                                           // generation arithmetic -> no init needed)
__device__ float gAb[K2B], gBb[K2B];       // block affine aggregates

// ---------------- K1: per-row prep (R5-proven access pattern) ----------------
__global__ void prep_kernel(const float* __restrict__ trace,
                            const float* __restrict__ sW, const float* __restrict__ sb,
                            const float* __restrict__ eW, const float* __restrict__ kp,
                            const float* __restrict__ thp,
                            float2* __restrict__ dc, float* __restrict__ seeds,
                            float* __restrict__ out)
{
    int n = blockIdx.x * blockDim.x + threadIdx.x;   // grid covers NPAD exactly
    if (n >= NSTEPS) { dc[n] = make_float2(0.f, 0.f); return; }
    const float2* r2 = (const float2*)(trace + (long)n * FEAT);
    float2 e0 = r2[0], e1 = r2[1], e2 = r2[2], e3 = r2[3], e4 = r2[4];
    float2 e5 = r2[5], e6 = r2[6], e7 = r2[7], e8 = r2[8];
    float tn1 = trace[(long)(n + 1) * FEAT];
    float d = tn1 - e0.x;
    float sig = sb[0];
    sig = fmaf(e1.x, sW[0], sig); sig = fmaf(e1.y, sW[1], sig);
    sig = fmaf(e2.x, sW[2], sig); sig = fmaf(e2.y, sW[3], sig);
    sig = fmaf(e3.x, sW[4], sig); sig = fmaf(e3.y, sW[5], sig);
    sig = fmaf(e4.x, sW[6], sig); sig = fmaf(e4.y, sW[7], sig);
    float ep = 0.f;
    ep = fmaf(e5.x, eW[0], ep); ep = fmaf(e5.y, eW[1], ep);
    ep = fmaf(e6.x, eW[2], ep); ep = fmaf(e6.y, eW[3], ep);
    ep = fmaf(e7.x, eW[4], ep); ep = fmaf(e7.y, eW[5], ep);
    ep = fmaf(e8.x, eW[6], ep); ep = fmaf(e8.y, eW[7], ep);
    float k = kp[0], th = thp[0];
    dc[n] = make_float2(d, sig * ep * sqrtf(fabsf(d)));
    out[NSTEPS + n]     = fmaf(-sig, sig, 2.f * k * th);  // regs
    out[2 * NSTEPS + n] = d;                              // dts
    if ((n & 3) == 0)                                     // ODE closed-form chunk seed
        seeds[n >> 2] = th + (trace[1] - th) * __expf(-k * (e0.x - trace[0]));
}

// one step + derivative-product update
#define GSTEP(dd, cc) { \
    float a   = fmaf(-k, (dd), 1.f); \
    float b   = kth * (dd); \
    float ar  = fabsf(r); \
    float sq  = sqrtf(ar); \
    float inv = (ar > 1e-30f) ? rsqrtf(ar) : 0.f; \
    float g   = fmaf(0.5f * (cc), copysignf(inv, r), a); \
    r = fmaf((cc), sq, fmaf(a, r, b)); \
    P *= g; }

#define FSTEP(dd, cc) { \
    float a = fmaf(-k, (dd), 1.f); \
    float b = kth * (dd); \
    rr = fmaf((cc), sqrtf(fabsf(rr)), fmaf(a, rr, b)); }

__device__ __forceinline__ void wave_scan_affine(float& A, float& B, int lane) {
#pragma unroll
    for (int d = 1; d < 64; d <<= 1) {
        float pA = __shfl_up(A, d, 64);
        float pB = __shfl_up(B, d, 64);
        if (lane >= d) { B = fmaf(A, pB, B); A *= pA; }
    }
}

// ---------------- K2: fused chunk + scan + final (R5-proven) ----------------
__global__ void __launch_bounds__(K2T) fused_pass(
    const float2* __restrict__ dc, const float* __restrict__ seeds,
    const float* __restrict__ trace,
    const float* __restrict__ kp, const float* __restrict__ thp,
    float* __restrict__ out)
{
    __shared__ float wAs[16], wBs[16];
    __shared__ float sgA[K2B], sgB[K2B];
    const int tid = threadIdx.x, lane = tid & 63, wid = tid >> 6, bid = blockIdx.x;
    const int c = bid * K2T + tid;
    const float k = kp[0], th = thp[0], kth = k * th;
    const float4 q0 = ((const float4*)dc)[2 * c];       // (d0,c0,d1,c1)
    const float4 q1 = ((const float4*)dc)[2 * c + 1];   // (d2,c2,d3,c3)
    const float s = seeds[c];

    // forward 4 steps from seed, derivative product -> affine map x -> A*x+B
    float r = s, P = 1.f;
    GSTEP(q0.x, q0.y)
    GSTEP(q0.z, q0.w)
    GSTEP(q1.x, q1.y)
    GSTEP(q1.z, q1.w)
    float A = P, B = fmaf(-P, s, r);

    // block-level inclusive scan over 1024 thread maps
    float iA = A, iB = B;
    wave_scan_affine(iA, iB, lane);
    if (lane == 63) { wAs[wid] = iA; wBs[wid] = iB; }
    __syncthreads();
    if (wid == 0) {
        float aA = (lane < 16) ? wAs[lane] : 1.f;
        float aB = (lane < 16) ? wBs[lane] : 0.f;
        wave_scan_affine(aA, aB, lane);
        if (lane < 16) { wAs[lane] = aA; wBs[lane] = aB; }
    }
    __syncthreads();
    float weA = 1.f, weB = 0.f;
    if (wid > 0) { weA = wAs[wid - 1]; weB = wBs[wid - 1]; }
    float eA = __shfl_up(iA, 1, 64), eB = __shfl_up(iB, 1, 64);
    if (lane == 0) { eA = 1.f; eB = 0.f; }
    float Ate = eA * weA;                 // thread-exclusive prefix within block
    float Bte = fmaf(eA, weB, eB);

    // publish block aggregate + init-free device-wide ticket barrier
    if (tid == 0) {
        __hip_atomic_store(&gAb[bid], wAs[15], __ATOMIC_RELAXED, __HIP_MEMORY_SCOPE_AGENT);
        __hip_atomic_store(&gBb[bid], wBs[15], __ATOMIC_RELEASE, __HIP_MEMORY_SCOPE_AGENT);
        unsigned int tk = __hip_atomic_fetch_add(&g_ticket, 1u, __ATOMIC_ACQ_REL,
                                                 __HIP_MEMORY_SCOPE_AGENT);
        unsigned int target = (tk / K2B + 1u) * K2B;
        while (__hip_atomic_load(&g_ticket, __ATOMIC_ACQUIRE, __HIP_MEMORY_SCOPE_AGENT) < target)
            __builtin_amdgcn_s_sleep(1);
    }
    __syncthreads();

    // every block redundantly scans the 256 block aggregates
    if (tid < K2B) {
        sgA[tid] = __hip_atomic_load(&gAb[tid], __ATOMIC_RELAXED, __HIP_MEMORY_SCOPE_AGENT);
        sgB[tid] = __hip_atomic_load(&gBb[tid], __ATOMIC_RELAXED, __HIP_MEMORY_SCOPE_AGENT);
    }
    __syncthreads();
    for (int d = 1; d < K2B; d <<= 1) {
        float pA = 1.f, pB = 0.f;
        bool act = (tid < K2B) && (tid >= d);
        if (act) { pA = sgA[tid - d]; pB = sgB[tid - d]; }
        __syncthreads();
        if (act) { sgB[tid] = fmaf(sgA[tid], pB, sgB[tid]); sgA[tid] *= pA; }
        __syncthreads();
    }
    float beA = 1.f, beB = 0.f;
    if (bid > 0) { beA = sgA[bid - 1]; beB = sgB[bid - 1]; }

    // corrected start for this thread's 4 steps, replay, store
    float FA = Ate * beA;
    float FB = fmaf(Ate, beB, Bte);
    float rr = fmaf(FA, trace[1], FB);
    float4 ov;
    FSTEP(q0.x, q0.y) ov.x = rr;
    FSTEP(q0.z, q0.w) ov.y = rr;
    FSTEP(q1.x, q1.y) ov.z = rr;
    FSTEP(q1.z, q1.w) ov.w = rr;
    int nb = 4 * c;
    if (nb + 4 <= NSTEPS) {
        *(float4*)(out + nb) = ov;
    } else {                       // last thread only (step NSTEPS is pad)
        out[nb + 0] = ov.x;
        out[nb + 1] = ov.y;
        out[nb + 2] = ov.z;
    }
}

extern "C" void kernel_launch(void* const* d_in, const int* in_sizes, int n_in,
                              void* d_out, int out_size, void* d_ws, size_t ws_size,
                              hipStream_t stream)
{
    const float* trace = (const float*)d_in[0];
    const float* sW    = (const float*)d_in[1];
    const float* sb    = (const float*)d_in[2];
    const float* eW    = (const float*)d_in[3];
    const float* kp    = (const float*)d_in[4];
    const float* thp   = (const float*)d_in[5];
    float* out = (float*)d_out;

    float*  w     = (float*)d_ws;
    float2* dc    = (float2*)w;          // NPAD float2 = 8 MB
    float*  seeds = w + 2 * NPAD;        // CHUNKS floats = 1 MB

    prep_kernel<<<NPAD / 256, 256, 0, stream>>>(trace, sW, sb, eW, kp, thp,
                                                dc, seeds, out);
    fused_pass<<<K2B, K2T, 0, stream>>>(dc, seeds, trace, kp, thp, out);
}